// Round 17
// baseline (185.738 us; speedup 1.0000x reference)
//
#include <hip/hip_runtime.h>
#include <hip/hip_bf16.h>

#define NN 50000      // nodes
#define MP 50176      // padded nodes (392 * 128)
#define NF 64         // features
#define NH 512        // hidden
#define NE 800000     // edges
#define NBK 196       // dst buckets (dst >> 8)
#define EBCAP 8192    // per-bucket capacity (2x Poisson mean 4082, sd 64)
#define ABLK 391      // bucketA blocks (x 2048 edges)
#define MB 392        // M blocks = MP/128
#define GRID (MB * 4) // 1568 = 8 * 196 (gemm1)
#define CPX (GRID / 8)
// gemm2 panel kernel: 4 col-stripes x 56 blocks, 7 m-tiles each
#define G2BLK 224
#define CPX2 (G2BLK / 8)   // 28
#define MTPB 7             // m-tiles per block (56 * 7 = 392)

typedef __attribute__((ext_vector_type(8))) short bf16x8;
typedef __attribute__((ext_vector_type(4))) float f32x4;

#define GLOAD16(g, l)                                                        \
    __builtin_amdgcn_global_load_lds(                                        \
        (const __attribute__((address_space(1))) unsigned int*)(g),          \
        (__attribute__((address_space(3))) unsigned int*)(l), 16, 0, 0)

__device__ __forceinline__ float bfu(unsigned short u) {
    union { float f; unsigned int i; } c;
    c.i = ((unsigned int)u) << 16;
    return c.f;
}

// ---------------------------------------------------------------------------
// detect whether edge_index is int64 (high dwords all zero) or int32
__global__ void detect_idx(const int* __restrict__ ei, int* __restrict__ flag) {
    if (threadIdx.x == 0 && blockIdx.x == 0) {
        int any = 0;
        for (int i = 0; i < 32; ++i) any |= ei[2 * i + 1];
        *flag = (any == 0) ? 1 : 0;   // 1 => int64 layout
    }
}

// ---------------------------------------------------------------------------
// Bucket sort pass A: partition edges into 196 dst-buckets (dst>>8).
// Payload packed into one int: (dst&255)<<16 | src  (src < 50000 < 2^16).
__global__ __launch_bounds__(256) void bucketA(const void* __restrict__ eiv,
                                               const int* __restrict__ flag,
                                               int* __restrict__ bcnt,
                                               int* __restrict__ ebP) {
    __shared__ int hist[NBK];
    __shared__ int lcur[NBK];
    const int tid = threadIdx.x;
    const int chunk = blockIdx.x * 2048;
    const int lim = min(2048, NE - chunk);
    const bool is64 = (*flag != 0);
    const long long* ei64 = (const long long*)eiv;
    const int* ei32 = (const int*)eiv;

    for (int i = tid; i < NBK; i += 256) hist[i] = 0;
    __syncthreads();
    for (int i = tid; i < lim; i += 256) {
        int d = is64 ? (int)ei64[NE + chunk + i] : ei32[NE + chunk + i];
        atomicAdd(&hist[d >> 8], 1);
    }
    __syncthreads();
    for (int i = tid; i < NBK; i += 256) {
        int c = hist[i];
        lcur[i] = c ? atomicAdd(&bcnt[i], c) : 0;   // reserve run in bucket i
    }
    __syncthreads();
    for (int i = tid; i < lim; i += 256) {
        int s, d;
        if (is64) { s = (int)ei64[chunk + i]; d = (int)ei64[NE + chunk + i]; }
        else      { s = ei32[chunk + i];      d = ei32[NE + chunk + i]; }
        int b = d >> 8;
        int p = atomicAdd(&lcur[b], 1);             // LDS cursor -> global slot
        ebP[b * EBCAP + p] = ((d & 255) << 16) | s;
    }
}

// exclusive scan of the NBK bucket counts (1 block) -> bucket bases
__global__ __launch_bounds__(256) void scan_bsum(const int* __restrict__ bsum,
                                                 int* __restrict__ boff) {
    __shared__ int sm[256];
    int tid = threadIdx.x;
    int v = (tid < NBK) ? bsum[tid] : 0;
    sm[tid] = v;
    __syncthreads();
    int acc = v;
#pragma unroll
    for (int off = 1; off < 256; off <<= 1) {
        int t = (tid >= off) ? sm[tid - off] : 0;
        __syncthreads();
        acc += t;
        sm[tid] = acc;
        __syncthreads();
    }
    if (tid < NBK) boff[tid] = acc - v;         // exclusive
}

// Bucket sort pass B: one block per bucket; LDS counting sort -> rowptr, csr.
__global__ __launch_bounds__(256) void bucketB(const int* __restrict__ ebP,
                                               const int* __restrict__ bcnt,
                                               const int* __restrict__ bbase,
                                               int* __restrict__ rowptr,
                                               int* __restrict__ csr) {
    __shared__ int hist[256], sm[256], curs[256];
    const int b = blockIdx.x;
    const int tid = threadIdx.x;
    const int n0 = b << 8;
    const int cnt = bcnt[b];
    const int base = bbase[b];

    hist[tid] = 0;
    __syncthreads();
    for (int i = tid; i < cnt; i += 256)
        atomicAdd(&hist[(ebP[b * EBCAP + i] >> 16) & 255], 1);
    __syncthreads();
    int v = hist[tid];
    sm[tid] = v;
    __syncthreads();
    int acc = v;
#pragma unroll
    for (int off = 1; off < 256; off <<= 1) {
        int t = (tid >= off) ? sm[tid - off] : 0;
        __syncthreads();
        acc += t;
        sm[tid] = acc;
        __syncthreads();
    }
    int excl = acc - v;
    if (n0 + tid < NN) rowptr[n0 + tid] = base + excl;   // coalesced
    curs[tid] = excl;
    __syncthreads();
    for (int i = tid; i < cnt; i += 256) {
        int p = ebP[b * EBCAP + i];
        int lp = atomicAdd(&curs[(p >> 16) & 255], 1);   // LDS cursor
        csr[base + lp] = p & 0xFFFF;
    }
    if (b == 0 && tid == 0) rowptr[NN] = NE;
}

// one launch for all fp32->bf16 conversions: x, W1^T, W2^T
#define XBLK  (NN * NF / 4 / 256)        // 3125
#define W1BLK (NF * NH / 256)            // 128
#define W2BLK (NH * NH / 256)            // 1024
__global__ __launch_bounds__(256) void cvt_all(const float* __restrict__ x,
                                               const float* __restrict__ W1,
                                               const float* __restrict__ W2,
                                               __hip_bfloat16* __restrict__ xb,
                                               __hip_bfloat16* __restrict__ w1t,
                                               __hip_bfloat16* __restrict__ w2t) {
    int bb = blockIdx.x;
    if (bb < XBLK) {
        int t = bb * 256 + threadIdx.x;
        float4 v = *(const float4*)&x[t * 4];
        union { ushort4 u; __hip_bfloat16 h[4]; } o;
        o.h[0] = __float2bfloat16(v.x);
        o.h[1] = __float2bfloat16(v.y);
        o.h[2] = __float2bfloat16(v.z);
        o.h[3] = __float2bfloat16(v.w);
        *(ushort4*)&xb[t * 4] = o.u;
    } else if (bb < XBLK + W1BLK) {
        int t = (bb - XBLK) * 256 + threadIdx.x;   // over NF*NH
        int n = t % NH, k = t / NH;
        w1t[n * NF + k] = __float2bfloat16(W1[t]);
    } else {
        int t = (bb - XBLK - W1BLK) * 256 + threadIdx.x;   // over NH*NH
        int n = t % NH, k = t / NH;
        w2t[n * NH + k] = __float2bfloat16(W2[t]);
    }
}

// gather-sum, one WAVE per node, 4 neighbor rows in flight per iteration.
__global__ __launch_bounds__(256) void gather(const __hip_bfloat16* __restrict__ xb,
                                              const int* __restrict__ rowptr,
                                              const int* __restrict__ csr,
                                              __hip_bfloat16* __restrict__ h0b) {
    int n = blockIdx.x * 4 + (threadIdx.x >> 6);   // node id
    int lane = threadIdx.x & 63;
    int g = lane >> 4;
    int f4 = (lane & 15) * 4;
    if (n >= MP) return;
    if (n >= NN) {
        if (g == 0)
            *(ushort4*)&h0b[(long long)n * NF + f4] = make_ushort4(0, 0, 0, 0);
        return;
    }
    float a0 = 0.f, a1 = 0.f, a2 = 0.f, a3 = 0.f;
    if (g == 0) {   // self term
        ushort4 v = *(const ushort4*)&xb[(long long)n * NF + f4];
        a0 = bfu(v.x); a1 = bfu(v.y); a2 = bfu(v.z); a3 = bfu(v.w);
    }
    int e0 = rowptr[n], e1 = rowptr[n + 1];
    for (int e = e0 + g; e < e1; e += 4) {
        int s = csr[e];                               // broadcast within group
        ushort4 v = *(const ushort4*)&xb[(long long)s * NF + f4];
        a0 += bfu(v.x); a1 += bfu(v.y); a2 += bfu(v.z); a3 += bfu(v.w);
    }
    a0 += __shfl_xor(a0, 16); a0 += __shfl_xor(a0, 32);
    a1 += __shfl_xor(a1, 16); a1 += __shfl_xor(a1, 32);
    a2 += __shfl_xor(a2, 16); a2 += __shfl_xor(a2, 32);
    a3 += __shfl_xor(a3, 16); a3 += __shfl_xor(a3, 32);
    if (g == 0) {
        union { ushort4 u; __hip_bfloat16 h[4]; } o;
        o.h[0] = __float2bfloat16(a0);
        o.h[1] = __float2bfloat16(a1);
        o.h[2] = __float2bfloat16(a2);
        o.h[3] = __float2bfloat16(a3);
        *(ushort4*)&h0b[(long long)n * NF + f4] = o.u;
    }
}

// ---------------------------------------------------------------------------
// GEMM1 (K=64): A staged via global_load_lds (issued first), B fragments read
// direct from L1-hot w1t while the DMA is in flight; single barrier.
__global__ __launch_bounds__(256) void gemm1_staged(const __hip_bfloat16* __restrict__ A,
                                                    const __hip_bfloat16* __restrict__ BT,
                                                    const float* __restrict__ bias,
                                                    __hip_bfloat16* __restrict__ C) {
    __shared__ __hip_bfloat16 As[128 * 64];   // 16 KB
    const int orig = blockIdx.x;
    const int L = (orig & 7) * CPX + (orig >> 3);
    const int mb = L >> 2, nb = L & 3;

    const int tid = threadIdx.x;
    const int lane = tid & 63;
    const int w = tid >> 6;
    const int wm = w >> 1, wn = w & 1;
    const long long rbase = (long long)mb * 128;
    const int nbase = nb * 128;
    const int r8  = lane >> 3;
    const int swc = (lane & 7) ^ r8;      // pre-swizzled global chunk (rule #21)
    const int key = lane & 7;
    const int lo = lane & 15, hi = lane >> 4;

    {
        const __hip_bfloat16* ga = A + (rbase + w * 32 + r8) * NF + swc * 8;
        __hip_bfloat16* la = As + (w * 32) * 64;
#pragma unroll
        for (int t = 0; t < 4; ++t)
            GLOAD16(ga + t * 8 * NF, la + t * 8 * 64);
    }
    bf16x8 bfr[2][4];
#pragma unroll
    for (int ks = 0; ks < 2; ++ks)
#pragma unroll
        for (int ni = 0; ni < 4; ++ni)
            bfr[ks][ni] = *(const bf16x8*)&BT[(nbase + wn * 64 + ni * 16 + lo) * NF +
                                             ks * 32 + hi * 8];
    __syncthreads();   // A landed

    f32x4 acc[4][4];
#pragma unroll
    for (int i = 0; i < 4; ++i)
#pragma unroll
        for (int j = 0; j < 4; ++j) acc[i][j] = (f32x4){0.f, 0.f, 0.f, 0.f};

#pragma unroll
    for (int ks = 0; ks < 2; ++ks) {
        bf16x8 af[4];
#pragma unroll
        for (int mi = 0; mi < 4; ++mi)
            af[mi] = *(const bf16x8*)&As[(wm * 64 + mi * 16 + lo) * 64 +
                                         (((ks * 4 + hi) ^ key) * 8)];
#pragma unroll
        for (int mi = 0; mi < 4; ++mi)
#pragma unroll
            for (int ni = 0; ni < 4; ++ni)
                acc[mi][ni] = __builtin_amdgcn_mfma_f32_16x16x32_bf16(
                    af[mi], bfr[ks][ni], acc[mi][ni], 0, 0, 0);
    }

    const int col0 = nbase + wn * 64 + lo;
    const long long row00 = rbase + wm * 64 + hi * 4;
#pragma unroll
    for (int ni = 0; ni < 4; ++ni) {
        int col = col0 + ni * 16;
        float bv = bias[col];
#pragma unroll
        for (int mi = 0; mi < 4; ++mi) {
            long long r0 = row00 + mi * 16;
#pragma unroll
            for (int r = 0; r < 4; ++r) {
                float v = fmaxf(acc[mi][ni][r] + bv, 0.f);   // ReLU
                C[(r0 + r) * NH + col] = __float2bfloat16(v);
            }
        }
    }
}

// ---------------------------------------------------------------------------
// GEMM2 (K=512): resident-B-panel kernel. Each block owns a 128-col stripe:
// B panel (128 x 512 = 128 KB, XOR-swizzled) loaded into LDS ONCE, then 7
// m-tiles of 128 rows processed with the proven counted-vmcnt A-only 2-deep
// pipeline (STAGE = 2 loads/wave, vmcnt(2), raw barriers). LDS = 160 KB,
// 1 block/CU, 512 threads (8 waves 2m x 4n, wave tile 64x32).
// Stats written per (mb, wm) slice directly to global (no LDS aliasing).
__global__ __launch_bounds__(512) void gemm2_panel(const __hip_bfloat16* __restrict__ A,
                                                   const __hip_bfloat16* __restrict__ BT,
                                                   const float* __restrict__ bias,
                                                   __hip_bfloat16* __restrict__ C,
                                                   float* __restrict__ partial) {
    constexpr int BK = 64;
    __shared__ __align__(16) char smem[163840];  // B 128KB | A dbuf 2x16KB
    __hip_bfloat16* Bp = (__hip_bfloat16*)smem;                  // [128][512]
    __hip_bfloat16* Ab0 = (__hip_bfloat16*)(smem + 131072);      // [128][64]
    __hip_bfloat16* Ab1 = (__hip_bfloat16*)(smem + 147456);

    const int orig = blockIdx.x;                 // 224 = 8 * 28
    const int L = (orig & 7) * CPX2 + (orig >> 3);
    const int stripe = L / 56;                   // 0..3
    const int q = L % 56;                        // 0..55 -> m-tiles q*7..q*7+6
    const int nbase = stripe * 128;

    const int tid = threadIdx.x;
    const int lane = tid & 63;
    const int w = tid >> 6;                      // wave 0..7
    const int wm = w >> 2, wn = w & 3;           // 2m x 4n (64 x 32 per wave)
    const int r8 = lane >> 3;
    const int swc = (lane & 7) ^ r8;             // pre-swizzled global chunk
    const int lo = lane & 15, hi = lane >> 4;

    // ---- load B panel once: wave w loads cols [w*16, w*16+16), swizzled ----
    {
        const int colbase = w * 16;
#pragma unroll
        for (int c = 0; c < 16; ++c) {
            int col = colbase + c;
            // LDS dest linear: Bp + col*512, lane covers 64 chunks of 8 elems.
            // global source chunk pre-swizzled in its low 3 bits by col&7.
            int gch = (lane & ~7) | ((lane & 7) ^ (col & 7));
            GLOAD16(BT + (long long)(nbase + col) * NH + gch * 8,
                    Bp + col * 512 + lane * 8);
        }
    }
    __syncthreads();   // B panel resident (drains vmcnt)

    for (int mt = 0; mt < MTPB; ++mt) {
        const int mb = q * MTPB + mt;
        const long long rbase = (long long)mb * 128;
        // per-wave A stage base: wave w stages rows [w*16, w*16+16)
        const __hip_bfloat16* gaBase =
            A + (rbase + w * 16 + r8) * (long long)NH + swc * 8;
        __hip_bfloat16* laBase0 = Ab0 + (w * 16) * BK;
        __hip_bfloat16* laBase1 = Ab1 + (w * 16) * BK;

        auto STAGE = [&](int s, int kb) {
            __hip_bfloat16* la = s ? laBase1 : laBase0;
#pragma unroll
            for (int t = 0; t < 2; ++t)
                GLOAD16(gaBase + kb + (long long)t * 8 * NH, la + t * 8 * BK);
        };

        f32x4 acc[4][2];
#pragma unroll
        for (int i = 0; i < 4; ++i)
#pragma unroll
            for (int j = 0; j < 2; ++j) acc[i][j] = (f32x4){0.f, 0.f, 0.f, 0.f};

        STAGE(0, 0);
        STAGE(1, BK);

#pragma unroll
        for (int t = 0; t < 8; ++t) {
            if (t == 7) { asm volatile("s_waitcnt vmcnt(0)" ::: "memory"); }
            else        { asm volatile("s_waitcnt vmcnt(2)" ::: "memory"); }
            __builtin_amdgcn_s_barrier();        // A tile t landed for all waves
            __builtin_amdgcn_sched_barrier(0);

            const __hip_bfloat16* Ac = (t & 1) ? Ab1 : Ab0;
#pragma unroll
            for (int ks = 0; ks < 2; ++ks) {
                bf16x8 af[4], bfr[2];
#pragma unroll
                for (int mi = 0; mi < 4; ++mi) {
                    int row = wm * 64 + mi * 16 + lo;
                    af[mi] = *(const bf16x8*)&Ac[row * BK +
                                                 (((ks * 4 + hi) ^ (row & 7)) * 8)];
                }
#pragma unroll
                for (int ni = 0; ni < 2; ++ni) {
                    int col = wn * 32 + ni * 16 + lo;
                    bfr[ni] = *(const bf16x8*)&Bp[col * 512 + t * 64 +
                                                  (((ks * 4 + hi) ^ (col & 7)) * 8)];
                }
#pragma unroll
                for (int mi = 0; mi < 4; ++mi)
#pragma unroll
                    for (int ni = 0; ni < 2; ++ni)
                        acc[mi][ni] = __builtin_amdgcn_mfma_f32_16x16x32_bf16(
                            af[mi], bfr[ni], acc[mi][ni], 0, 0, 0);
            }
            __builtin_amdgcn_sched_barrier(0);
            __builtin_amdgcn_s_barrier();        // all waves done reading tile t
            __builtin_amdgcn_sched_barrier(0);
            if (t < 6) STAGE(t & 1, (t + 2) * BK);
        }

        // epilogue (no LDS): bias + C write + per-(mb,wm)-slice stats
        const int col0 = nbase + wn * 32 + lo;
        const long long row00 = rbase + wm * 64 + hi * 4;
#pragma unroll
        for (int ni = 0; ni < 2; ++ni) {
            int col = col0 + ni * 16;
            float bv = bias[col];
            float s = 0.f, qq = 0.f;
#pragma unroll
            for (int mi = 0; mi < 4; ++mi) {
                long long r0 = row00 + mi * 16;
#pragma unroll
                for (int r = 0; r < 4; ++r) {
                    float v = acc[mi][ni][r] + bv;
                    C[(r0 + r) * NH + col] = __float2bfloat16(v);
                    if ((r0 + r) < NN) { s += v; qq += v * v; }
                }
            }
            s  += __shfl_xor(s, 16);  s += __shfl_xor(s, 32);
            qq += __shfl_xor(qq, 16); qq += __shfl_xor(qq, 32);
            if (lane < 16) {   // slice = mb*2 + wm ; cols disjoint per block
                int cc = nbase + wn * 32 + ni * 16 + lane;
                partial[(mb * 2 + wm) * 1024 + cc] = s;
                partial[(mb * 2 + wm) * 1024 + 512 + cc] = qq;
            }
        }
    }
}

// reduce per-slice partials: stats[j] = sum over 784 slices, j<1024
__global__ __launch_bounds__(256) void stats_reduce(const float* __restrict__ partial,
                                                    float* __restrict__ stats) {
    int j = blockIdx.x * 256 + threadIdx.x;   // 0..1023
    float s = 0.f;
    for (int sl = 0; sl < MB * 2; ++sl) s += partial[sl * 1024 + j];
    stats[j] = s;
}

// BN(train stats) + ReLU + classifier fused; bf16 h2, per-lane register params
__global__ __launch_bounds__(256) void bn_cls(const __hip_bfloat16* __restrict__ h2b,
                                              const float* __restrict__ stats,
                                              const float* __restrict__ gamma,
                                              const float* __restrict__ beta,
                                              const float* __restrict__ Wc,
                                              const float* __restrict__ bc,
                                              float* __restrict__ out) {
    int tid = threadIdx.x;
    int lane = tid & 63;
    int k0 = lane * 8;
    float sc[8], sh[8], w0[8], w1[8];
#pragma unroll
    for (int j = 0; j < 8; ++j) {
        int k = k0 + j;
        float mean = stats[k] * (1.0f / NN);
        float var = stats[512 + k] * (1.0f / NN) - mean * mean;
        float rs = rsqrtf(var + 1e-5f);
        float s = gamma[k] * rs;
        sc[j] = s;
        sh[j] = beta[k] - mean * s;
        w0[j] = Wc[2 * k];
        w1[j] = Wc[2 * k + 1];
    }
    float bc0 = bc[0], bc1 = bc[1];
    int wid = blockIdx.x * 4 + (tid >> 6);
    int nw = gridDim.x * 4;
    for (int row = wid; row < NN; row += nw) {
        bf16x8 v8 = *(const bf16x8*)&h2b[(long long)row * NH + k0];
        float a0 = 0.f, a1 = 0.f;
#pragma unroll
        for (int j = 0; j < 8; ++j) {
            float v = __bfloat162float(((const __hip_bfloat16*)&v8)[j]);
            float hn = fmaxf(fmaf(v, sc[j], sh[j]), 0.f);
            a0 = fmaf(hn, w0[j], a0);
            a1 = fmaf(hn, w1[j], a1);
        }
#pragma unroll
        for (int off = 32; off; off >>= 1) {
            a0 += __shfl_xor(a0, off);
            a1 += __shfl_xor(a1, off);
        }
        if (lane == 0) {
            out[(long long)row * 2 + 0] = a0 + bc0;
            out[(long long)row * 2 + 1] = a1 + bc1;
        }
    }
}

// ---------------------------------------------------------------------------
extern "C" void kernel_launch(void* const* d_in, const int* in_sizes, int n_in,
                              void* d_out, int out_size, void* d_ws, size_t ws_size,
                              hipStream_t stream) {
    const float* x     = (const float*)d_in[0];
    const void*  ei    = d_in[1];
    const float* W1    = (const float*)d_in[2];
    const float* b1    = (const float*)d_in[3];
    const float* W2    = (const float*)d_in[4];
    const float* b2    = (const float*)d_in[5];
    const float* gamma = (const float*)d_in[6];
    const float* beta  = (const float*)d_in[7];
    const float* Wc    = (const float*)d_in[8];
    const float* bc    = (const float*)d_in[9];
    float* out = (float*)d_out;

    // workspace carve-up (256B aligned)
    char* base = (char*)d_ws;
    size_t o = 0;
    auto alloc = [&](size_t bytes) {
        char* p = base + o;
        o = (o + bytes + 255) & ~(size_t)255;
        return p;
    };
    __hip_bfloat16* h0b     = (__hip_bfloat16*)alloc((size_t)MP * NF * 2);
    __hip_bfloat16* h1b     = (__hip_bfloat16*)alloc((size_t)MP * NH * 2);
    __hip_bfloat16* h2b     = (__hip_bfloat16*)alloc((size_t)MP * NH * 2);
    __hip_bfloat16* xb      = (__hip_bfloat16*)alloc((size_t)NN * NF * 2);
    __hip_bfloat16* w1t     = (__hip_bfloat16*)alloc((size_t)NH * NF * 2);
    __hip_bfloat16* w2t     = (__hip_bfloat16*)alloc((size_t)NH * NH * 2);
    int*            ebP     = (int*)alloc((size_t)NBK * EBCAP * 4);
    int*            bcnt    = (int*)alloc(256 * 4);
    int*            bbase   = (int*)alloc(256 * 4);
    int*            rowptr  = (int*)alloc((size_t)(NN + 1) * 4);
    int*            csr     = (int*)alloc((size_t)NE * 4);
    float*          partial = (float*)alloc((size_t)MB * 2 * 1024 * 4);
    float*          stats   = (float*)alloc(1024 * 4);
    int*            flag    = (int*)alloc(256);

    hipMemsetAsync(bcnt, 0, NBK * 4, stream);
    detect_idx<<<1, 1, 0, stream>>>((const int*)ei, flag);

    // CSR build via 2-pass LDS bucket sort (no scattered global atomics)
    bucketA<<<ABLK, 256, 0, stream>>>(ei, flag, bcnt, ebP);
    scan_bsum<<<1, 256, 0, stream>>>(bcnt, bbase);
    bucketB<<<NBK, 256, 0, stream>>>(ebP, bcnt, bbase, rowptr, csr);

    cvt_all<<<XBLK + W1BLK + W2BLK, 256, 0, stream>>>(x, W1, W2, xb, w1t, w2t);
    gather<<<MP / 4, 256, 0, stream>>>(xb, rowptr, csr, h0b);

    gemm1_staged<<<GRID, 256, 0, stream>>>(h0b, w1t, b1, h1b);
    gemm2_panel<<<G2BLK, 512, 0, stream>>>(h1b, w2t, b2, h2b, partial);

    stats_reduce<<<4, 256, 0, stream>>>(partial, stats);
    bn_cls<<<512, 256, 0, stream>>>(h2b, stats, gamma, beta, Wc, bc, out);
}

// Round 18
// 162.136 us; speedup vs baseline: 1.1456x; 1.1456x over previous
//
#include <hip/hip_runtime.h>
#include <hip/hip_bf16.h>

#define NN 50000      // nodes
#define MP 50176      // padded nodes (392 * 128)
#define NF 64         // features
#define NH 512        // hidden
#define NE 800000     // edges
#define NBK 196       // dst buckets (dst >> 8)
#define EBCAP 8192    // per-bucket capacity (2x Poisson mean 4082, sd 64)
#define ABLK 391      // bucketA blocks (x 2048 edges)
#define MB 392        // M blocks = MP/128
#define GRID (MB * 4) // 1568 = 8 * 196
#define CPX (GRID / 8)

typedef __attribute__((ext_vector_type(8))) short bf16x8;
typedef __attribute__((ext_vector_type(4))) float f32x4;

#define GLOAD16(g, l)                                                        \
    __builtin_amdgcn_global_load_lds(                                        \
        (const __attribute__((address_space(1))) unsigned int*)(g),          \
        (__attribute__((address_space(3))) unsigned int*)(l), 16, 0, 0)

__device__ __forceinline__ float bfu(unsigned short u) {
    union { float f; unsigned int i; } c;
    c.i = ((unsigned int)u) << 16;
    return c.f;
}

// ---------------------------------------------------------------------------
// detect edge_index width (int64 high dwords all zero) AND zero bcnt
// (folds the former hipMemsetAsync dispatch into this 1-thread kernel).
__global__ void detect_idx(const int* __restrict__ ei, int* __restrict__ flag,
                           int* __restrict__ bcnt) {
    if (threadIdx.x == 0 && blockIdx.x == 0) {
        int any = 0;
        for (int i = 0; i < 32; ++i) any |= ei[2 * i + 1];
        *flag = (any == 0) ? 1 : 0;   // 1 => int64 layout
        for (int i = 0; i < NBK; ++i) bcnt[i] = 0;
    }
}

// ---------------------------------------------------------------------------
// Bucket sort pass A: partition edges into 196 dst-buckets (dst>>8).
// Payload packed into one int: (dst&255)<<16 | src  (src < 50000 < 2^16).
__global__ __launch_bounds__(256) void bucketA(const void* __restrict__ eiv,
                                               const int* __restrict__ flag,
                                               int* __restrict__ bcnt,
                                               int* __restrict__ ebP) {
    __shared__ int hist[NBK];
    __shared__ int lcur[NBK];
    const int tid = threadIdx.x;
    const int chunk = blockIdx.x * 2048;
    const int lim = min(2048, NE - chunk);
    const bool is64 = (*flag != 0);
    const long long* ei64 = (const long long*)eiv;
    const int* ei32 = (const int*)eiv;

    for (int i = tid; i < NBK; i += 256) hist[i] = 0;
    __syncthreads();
    for (int i = tid; i < lim; i += 256) {
        int d = is64 ? (int)ei64[NE + chunk + i] : ei32[NE + chunk + i];
        atomicAdd(&hist[d >> 8], 1);
    }
    __syncthreads();
    for (int i = tid; i < NBK; i += 256) {
        int c = hist[i];
        lcur[i] = c ? atomicAdd(&bcnt[i], c) : 0;   // reserve run in bucket i
    }
    __syncthreads();
    for (int i = tid; i < lim; i += 256) {
        int s, d;
        if (is64) { s = (int)ei64[chunk + i]; d = (int)ei64[NE + chunk + i]; }
        else      { s = ei32[chunk + i];      d = ei32[NE + chunk + i]; }
        int b = d >> 8;
        int p = atomicAdd(&lcur[b], 1);             // LDS cursor -> global slot
        ebP[b * EBCAP + p] = ((d & 255) << 16) | s;
    }
}

// Bucket sort pass B: one block per bucket; computes its OWN base (masked
// scan over the 196 L2-hot bucket counts — replaces the scan_bsum dispatch),
// then LDS counting sort -> rowptr, csr.
__global__ __launch_bounds__(256) void bucketB(const int* __restrict__ ebP,
                                               const int* __restrict__ bcnt,
                                               int* __restrict__ rowptr,
                                               int* __restrict__ csr) {
    __shared__ int hist[256], sm[256], curs[256];
    __shared__ int baseSm;
    const int b = blockIdx.x;
    const int tid = threadIdx.x;
    const int n0 = b << 8;
    const int cnt = bcnt[b];

    // --- base = sum of bcnt[0..b-1] via in-block masked scan ---
    {
        int v = (tid < b && tid < NBK) ? bcnt[tid] : 0;
        sm[tid] = v;
        __syncthreads();
        int acc = v;
#pragma unroll
        for (int off = 1; off < 256; off <<= 1) {
            int t = (tid >= off) ? sm[tid - off] : 0;
            __syncthreads();
            acc += t;
            sm[tid] = acc;
            __syncthreads();
        }
        if (tid == 255) baseSm = acc;
        __syncthreads();
    }
    const int base = baseSm;

    hist[tid] = 0;
    __syncthreads();
    for (int i = tid; i < cnt; i += 256)
        atomicAdd(&hist[(ebP[b * EBCAP + i] >> 16) & 255], 1);
    __syncthreads();
    int v = hist[tid];
    sm[tid] = v;
    __syncthreads();
    int acc = v;
#pragma unroll
    for (int off = 1; off < 256; off <<= 1) {
        int t = (tid >= off) ? sm[tid - off] : 0;
        __syncthreads();
        acc += t;
        sm[tid] = acc;
        __syncthreads();
    }
    int excl = acc - v;
    if (n0 + tid < NN) rowptr[n0 + tid] = base + excl;   // coalesced
    curs[tid] = excl;
    __syncthreads();
    for (int i = tid; i < cnt; i += 256) {
        int p = ebP[b * EBCAP + i];
        int lp = atomicAdd(&curs[(p >> 16) & 255], 1);   // LDS cursor
        csr[base + lp] = p & 0xFFFF;
    }
    if (b == 0 && tid == 0) rowptr[NN] = NE;
}

// one launch for all fp32->bf16 conversions: x, W1^T, W2^T
#define XBLK  (NN * NF / 4 / 256)        // 3125
#define W1BLK (NF * NH / 256)            // 128
#define W2BLK (NH * NH / 256)            // 1024
__global__ __launch_bounds__(256) void cvt_all(const float* __restrict__ x,
                                               const float* __restrict__ W1,
                                               const float* __restrict__ W2,
                                               __hip_bfloat16* __restrict__ xb,
                                               __hip_bfloat16* __restrict__ w1t,
                                               __hip_bfloat16* __restrict__ w2t) {
    int bb = blockIdx.x;
    if (bb < XBLK) {
        int t = bb * 256 + threadIdx.x;
        float4 v = *(const float4*)&x[t * 4];
        union { ushort4 u; __hip_bfloat16 h[4]; } o;
        o.h[0] = __float2bfloat16(v.x);
        o.h[1] = __float2bfloat16(v.y);
        o.h[2] = __float2bfloat16(v.z);
        o.h[3] = __float2bfloat16(v.w);
        *(ushort4*)&xb[t * 4] = o.u;
    } else if (bb < XBLK + W1BLK) {
        int t = (bb - XBLK) * 256 + threadIdx.x;   // over NF*NH
        int n = t % NH, k = t / NH;
        w1t[n * NF + k] = __float2bfloat16(W1[t]);
    } else {
        int t = (bb - XBLK - W1BLK) * 256 + threadIdx.x;   // over NH*NH
        int n = t % NH, k = t / NH;
        w2t[n * NH + k] = __float2bfloat16(W2[t]);
    }
}

// gather-sum, one WAVE per node, 4 neighbor rows in flight per iteration.
__global__ __launch_bounds__(256) void gather(const __hip_bfloat16* __restrict__ xb,
                                              const int* __restrict__ rowptr,
                                              const int* __restrict__ csr,
                                              __hip_bfloat16* __restrict__ h0b) {
    int n = blockIdx.x * 4 + (threadIdx.x >> 6);   // node id
    int lane = threadIdx.x & 63;
    int g = lane >> 4;
    int f4 = (lane & 15) * 4;
    if (n >= MP) return;
    if (n >= NN) {
        if (g == 0)
            *(ushort4*)&h0b[(long long)n * NF + f4] = make_ushort4(0, 0, 0, 0);
        return;
    }
    float a0 = 0.f, a1 = 0.f, a2 = 0.f, a3 = 0.f;
    if (g == 0) {   // self term
        ushort4 v = *(const ushort4*)&xb[(long long)n * NF + f4];
        a0 = bfu(v.x); a1 = bfu(v.y); a2 = bfu(v.z); a3 = bfu(v.w);
    }
    int e0 = rowptr[n], e1 = rowptr[n + 1];
    for (int e = e0 + g; e < e1; e += 4) {
        int s = csr[e];                               // broadcast within group
        ushort4 v = *(const ushort4*)&xb[(long long)s * NF + f4];
        a0 += bfu(v.x); a1 += bfu(v.y); a2 += bfu(v.z); a3 += bfu(v.w);
    }
    a0 += __shfl_xor(a0, 16); a0 += __shfl_xor(a0, 32);
    a1 += __shfl_xor(a1, 16); a1 += __shfl_xor(a1, 32);
    a2 += __shfl_xor(a2, 16); a2 += __shfl_xor(a2, 32);
    a3 += __shfl_xor(a3, 16); a3 += __shfl_xor(a3, 32);
    if (g == 0) {
        union { ushort4 u; __hip_bfloat16 h[4]; } o;
        o.h[0] = __float2bfloat16(a0);
        o.h[1] = __float2bfloat16(a1);
        o.h[2] = __float2bfloat16(a2);
        o.h[3] = __float2bfloat16(a3);
        *(ushort4*)&h0b[(long long)n * NF + f4] = o.u;
    }
}

// ---------------------------------------------------------------------------
// GEMM1 (K=64): A staged via global_load_lds (issued first), B fragments read
// direct from L1-hot w1t while the DMA is in flight; single barrier.
__global__ __launch_bounds__(256) void gemm1_staged(const __hip_bfloat16* __restrict__ A,
                                                    const __hip_bfloat16* __restrict__ BT,
                                                    const float* __restrict__ bias,
                                                    __hip_bfloat16* __restrict__ C) {
    __shared__ __hip_bfloat16 As[128 * 64];   // 16 KB
    const int orig = blockIdx.x;
    const int L = (orig & 7) * CPX + (orig >> 3);
    const int mb = L >> 2, nb = L & 3;

    const int tid = threadIdx.x;
    const int lane = tid & 63;
    const int w = tid >> 6;
    const int wm = w >> 1, wn = w & 1;
    const long long rbase = (long long)mb * 128;
    const int nbase = nb * 128;
    const int r8  = lane >> 3;
    const int swc = (lane & 7) ^ r8;      // pre-swizzled global chunk (rule #21)
    const int key = lane & 7;
    const int lo = lane & 15, hi = lane >> 4;

    {
        const __hip_bfloat16* ga = A + (rbase + w * 32 + r8) * NF + swc * 8;
        __hip_bfloat16* la = As + (w * 32) * 64;
#pragma unroll
        for (int t = 0; t < 4; ++t)
            GLOAD16(ga + t * 8 * NF, la + t * 8 * 64);
    }
    bf16x8 bfr[2][4];
#pragma unroll
    for (int ks = 0; ks < 2; ++ks)
#pragma unroll
        for (int ni = 0; ni < 4; ++ni)
            bfr[ks][ni] = *(const bf16x8*)&BT[(nbase + wn * 64 + ni * 16 + lo) * NF +
                                             ks * 32 + hi * 8];
    __syncthreads();   // A landed

    f32x4 acc[4][4];
#pragma unroll
    for (int i = 0; i < 4; ++i)
#pragma unroll
        for (int j = 0; j < 4; ++j) acc[i][j] = (f32x4){0.f, 0.f, 0.f, 0.f};

#pragma unroll
    for (int ks = 0; ks < 2; ++ks) {
        bf16x8 af[4];
#pragma unroll
        for (int mi = 0; mi < 4; ++mi)
            af[mi] = *(const bf16x8*)&As[(wm * 64 + mi * 16 + lo) * 64 +
                                         (((ks * 4 + hi) ^ key) * 8)];
#pragma unroll
        for (int mi = 0; mi < 4; ++mi)
#pragma unroll
            for (int ni = 0; ni < 4; ++ni)
                acc[mi][ni] = __builtin_amdgcn_mfma_f32_16x16x32_bf16(
                    af[mi], bfr[ks][ni], acc[mi][ni], 0, 0, 0);
    }

    const int col0 = nbase + wn * 64 + lo;
    const long long row00 = rbase + wm * 64 + hi * 4;
#pragma unroll
    for (int ni = 0; ni < 4; ++ni) {
        int col = col0 + ni * 16;
        float bv = bias[col];
#pragma unroll
        for (int mi = 0; mi < 4; ++mi) {
            long long r0 = row00 + mi * 16;
#pragma unroll
            for (int r = 0; r < 4; ++r) {
                float v = fmaxf(acc[mi][ni][r] + bv, 0.f);   // ReLU
                C[(r0 + r) * NH + col] = __float2bfloat16(v);
            }
        }
    }
}

// ---------------------------------------------------------------------------
// GEMM2 (K=512): counted-vmcnt 2-deep pipeline (R13/R16 proven form).
__global__ __launch_bounds__(256) void gemm2_db(const __hip_bfloat16* __restrict__ A,
                                                const __hip_bfloat16* __restrict__ BT,
                                                const float* __restrict__ bias,
                                                __hip_bfloat16* __restrict__ C,
                                                float* __restrict__ partial) {
    constexpr int BK = 64;
    __shared__ __align__(16) char smem[65536];   // 2 sets x (A 16KB | B 16KB)
    float* smsum = (float*)smem;                 // alias set0 (dead after loop)
    float* smsq  = (float*)(smem + 2048);

    const int orig = blockIdx.x;
    const int L = (orig & 7) * CPX + (orig >> 3);
    const int mb = L >> 2, nb = L & 3;

    const int tid = threadIdx.x;
    const int lane = tid & 63;
    const int w = tid >> 6;
    const int wm = w >> 1, wn = w & 1;
    const long long rbase = (long long)mb * 128;
    const int nbase = nb * 128;
    const int r8  = lane >> 3;            // stage row within 8-row group
    const int swc = (lane & 7) ^ r8;      // pre-swizzled global chunk (rule #21)
    const int key = lane & 7;             // read-side swizzle key
    const int lo = lane & 15, hi = lane >> 4;

    const __hip_bfloat16* gaBase =
        A + (rbase + w * 32 + r8) * (long long)NH + swc * 8;
    const __hip_bfloat16* gbBase =
        BT + (long long)(nbase + w * 32 + r8) * NH + swc * 8;
    const int laOff = (w * 32) * BK;

    auto STAGE = [&](int s, int kb) {
        __hip_bfloat16* la = (__hip_bfloat16*)(smem + s * 32768) + laOff;
        __hip_bfloat16* lb = (__hip_bfloat16*)(smem + s * 32768 + 16384) + laOff;
#pragma unroll
        for (int t = 0; t < 4; ++t)
            GLOAD16(gaBase + kb + (long long)t * 8 * NH, la + t * 8 * BK);
#pragma unroll
        for (int t = 0; t < 4; ++t)
            GLOAD16(gbBase + kb + (long long)t * 8 * NH, lb + t * 8 * BK);
    };

    f32x4 acc[4][4];
#pragma unroll
    for (int i = 0; i < 4; ++i)
#pragma unroll
        for (int j = 0; j < 4; ++j) acc[i][j] = (f32x4){0.f, 0.f, 0.f, 0.f};

    // prologue: 2-deep prefetch (16 loads outstanding per wave)
    STAGE(0, 0);
    STAGE(1, BK);

#pragma unroll
    for (int t = 0; t < 8; ++t) {
        if (t == 7) { asm volatile("s_waitcnt vmcnt(0)" ::: "memory"); }
        else        { asm volatile("s_waitcnt vmcnt(8)" ::: "memory"); }
        __builtin_amdgcn_s_barrier();          // all waves' DMA for cur landed
        __builtin_amdgcn_sched_barrier(0);

        const __hip_bfloat16* Ac = (const __hip_bfloat16*)(smem + (t & 1) * 32768);
        const __hip_bfloat16* Bc = Ac + 8192;  // +16384 bytes
        __builtin_amdgcn_s_setprio(1);
#pragma unroll
        for (int ks = 0; ks < 2; ++ks) {
            bf16x8 af[4], bfr[4];
#pragma unroll
            for (int mi = 0; mi < 4; ++mi)
                af[mi] = *(const bf16x8*)&Ac[(wm * 64 + mi * 16 + lo) * BK +
                                             (((ks * 4 + hi) ^ key) * 8)];
#pragma unroll
            for (int ni = 0; ni < 4; ++ni)
                bfr[ni] = *(const bf16x8*)&Bc[(wn * 64 + ni * 16 + lo) * BK +
                                              (((ks * 4 + hi) ^ key) * 8)];
#pragma unroll
            for (int mi = 0; mi < 4; ++mi)
#pragma unroll
                for (int ni = 0; ni < 4; ++ni)
                    acc[mi][ni] = __builtin_amdgcn_mfma_f32_16x16x32_bf16(
                        af[mi], bfr[ni], acc[mi][ni], 0, 0, 0);
        }
        __builtin_amdgcn_s_setprio(0);
        __builtin_amdgcn_sched_barrier(0);
        __builtin_amdgcn_s_barrier();          // all waves done reading cur
        __builtin_amdgcn_sched_barrier(0);
        if (t < 6) STAGE(t & 1, (t + 2) * BK); // refill freed buffer, 2 ahead
    }

    // epilogue: vmcnt==0 here; full barrier before LDS alias reuse
    __syncthreads();
    if (tid < 128) { smsum[tid] = 0.f; smsq[tid] = 0.f; }
    __syncthreads();
    const int col0 = nbase + wn * 64 + lo;
    const long long row00 = rbase + wm * 64 + hi * 4;
#pragma unroll
    for (int ni = 0; ni < 4; ++ni) {
        int col = col0 + ni * 16;
        float bv = bias[col];
        float s = 0.f, q = 0.f;
#pragma unroll
        for (int mi = 0; mi < 4; ++mi) {
            long long r0 = row00 + mi * 16;
#pragma unroll
            for (int r = 0; r < 4; ++r) {
                float v = acc[mi][ni][r] + bv;
                C[(r0 + r) * NH + col] = __float2bfloat16(v);
                if ((r0 + r) < NN) { s += v; q += v * v; }
            }
        }
        s += __shfl_xor(s, 16); s += __shfl_xor(s, 32);
        q += __shfl_xor(q, 16); q += __shfl_xor(q, 32);
        if (lane < 16) {
            atomicAdd(&smsum[wn * 64 + ni * 16 + lane], s);
            atomicAdd(&smsq[wn * 64 + ni * 16 + lane], q);
        }
    }
    __syncthreads();
    if (tid < 128) {
        partial[mb * 1024 + nbase + tid] = smsum[tid];
        partial[mb * 1024 + 512 + nbase + tid] = smsq[tid];
    }
}

// reduce per-block partials: stats[j] = sum_mb partial[mb*1024 + j], j<1024
__global__ __launch_bounds__(256) void stats_reduce(const float* __restrict__ partial,
                                                    float* __restrict__ stats) {
    int j = blockIdx.x * 256 + threadIdx.x;   // 0..1023
    float s = 0.f;
    for (int mb = 0; mb < MB; ++mb) s += partial[mb * 1024 + j];
    stats[j] = s;
}

// BN(train stats) + ReLU + classifier fused; bf16 h2, per-lane register params
__global__ __launch_bounds__(256) void bn_cls(const __hip_bfloat16* __restrict__ h2b,
                                              const float* __restrict__ stats,
                                              const float* __restrict__ gamma,
                                              const float* __restrict__ beta,
                                              const float* __restrict__ Wc,
                                              const float* __restrict__ bc,
                                              float* __restrict__ out) {
    int tid = threadIdx.x;
    int lane = tid & 63;
    int k0 = lane * 8;
    float sc[8], sh[8], w0[8], w1[8];
#pragma unroll
    for (int j = 0; j < 8; ++j) {
        int k = k0 + j;
        float mean = stats[k] * (1.0f / NN);
        float var = stats[512 + k] * (1.0f / NN) - mean * mean;
        float rs = rsqrtf(var + 1e-5f);
        float s = gamma[k] * rs;
        sc[j] = s;
        sh[j] = beta[k] - mean * s;
        w0[j] = Wc[2 * k];
        w1[j] = Wc[2 * k + 1];
    }
    float bc0 = bc[0], bc1 = bc[1];
    int wid = blockIdx.x * 4 + (tid >> 6);
    int nw = gridDim.x * 4;
    for (int row = wid; row < NN; row += nw) {
        bf16x8 v8 = *(const bf16x8*)&h2b[(long long)row * NH + k0];
        float a0 = 0.f, a1 = 0.f;
#pragma unroll
        for (int j = 0; j < 8; ++j) {
            float v = __bfloat162float(((const __hip_bfloat16*)&v8)[j]);
            float hn = fmaxf(fmaf(v, sc[j], sh[j]), 0.f);
            a0 = fmaf(hn, w0[j], a0);
            a1 = fmaf(hn, w1[j], a1);
        }
#pragma unroll
        for (int off = 32; off; off >>= 1) {
            a0 += __shfl_xor(a0, off);
            a1 += __shfl_xor(a1, off);
        }
        if (lane == 0) {
            out[(long long)row * 2 + 0] = a0 + bc0;
            out[(long long)row * 2 + 1] = a1 + bc1;
        }
    }
}

// ---------------------------------------------------------------------------
extern "C" void kernel_launch(void* const* d_in, const int* in_sizes, int n_in,
                              void* d_out, int out_size, void* d_ws, size_t ws_size,
                              hipStream_t stream) {
    const float* x     = (const float*)d_in[0];
    const void*  ei    = d_in[1];
    const float* W1    = (const float*)d_in[2];
    const float* b1    = (const float*)d_in[3];
    const float* W2    = (const float*)d_in[4];
    const float* b2    = (const float*)d_in[5];
    const float* gamma = (const float*)d_in[6];
    const float* beta  = (const float*)d_in[7];
    const float* Wc    = (const float*)d_in[8];
    const float* bc    = (const float*)d_in[9];
    float* out = (float*)d_out;

    // workspace carve-up (256B aligned)
    char* base = (char*)d_ws;
    size_t o = 0;
    auto alloc = [&](size_t bytes) {
        char* p = base + o;
        o = (o + bytes + 255) & ~(size_t)255;
        return p;
    };
    __hip_bfloat16* h0b     = (__hip_bfloat16*)alloc((size_t)MP * NF * 2);
    __hip_bfloat16* h1b     = (__hip_bfloat16*)alloc((size_t)MP * NH * 2);
    __hip_bfloat16* h2b     = (__hip_bfloat16*)alloc((size_t)MP * NH * 2);
    __hip_bfloat16* xb      = (__hip_bfloat16*)alloc((size_t)NN * NF * 2);
    __hip_bfloat16* w1t     = (__hip_bfloat16*)alloc((size_t)NH * NF * 2);
    __hip_bfloat16* w2t     = (__hip_bfloat16*)alloc((size_t)NH * NH * 2);
    int*            ebP     = (int*)alloc((size_t)NBK * EBCAP * 4);
    int*            bcnt    = (int*)alloc(256 * 4);
    int*            rowptr  = (int*)alloc((size_t)(NN + 1) * 4);
    int*            csr     = (int*)alloc((size_t)NE * 4);
    float*          partial = (float*)alloc((size_t)MB * 1024 * 4);
    float*          stats   = (float*)alloc(1024 * 4);
    int*            flag    = (int*)alloc(256);

    // CSR build via 2-pass LDS bucket sort (no scattered global atomics)
    detect_idx<<<1, 1, 0, stream>>>((const int*)ei, flag, bcnt);
    bucketA<<<ABLK, 256, 0, stream>>>(ei, flag, bcnt, ebP);
    bucketB<<<NBK, 256, 0, stream>>>(ebP, bcnt, rowptr, csr);

    cvt_all<<<XBLK + W1BLK + W2BLK, 256, 0, stream>>>(x, W1, W2, xb, w1t, w2t);
    gather<<<MP / 4, 256, 0, stream>>>(xb, rowptr, csr, h0b);

    gemm1_staged<<<GRID, 256, 0, stream>>>(h0b, w1t, b1, h1b);
    gemm2_db<<<GRID, 256, 0, stream>>>(h1b, w2t, b2, h2b, partial);

    stats_reduce<<<4, 256, 0, stream>>>(partial, stats);
    bn_cls<<<512, 256, 0, stream>>>(h2b, stats, gamma, beta, Wc, bc, out);
}

// Round 19
// 148.518 us; speedup vs baseline: 1.2506x; 1.0917x over previous
//
#include <hip/hip_runtime.h>
#include <hip/hip_bf16.h>

#define NN 50000      // nodes
#define MP 50176      // padded nodes (392 * 128)
#define NF 64         // features
#define NH 512        // hidden
#define NE 800000     // edges
#define NBK 196       // dst buckets (dst >> 8)
#define EBCAP 8192    // per-bucket capacity (2x Poisson mean 4082, sd 64)
#define ABLK 391      // bucketA blocks (x 2048 edges)
#define MB 392        // M blocks = MP/128
#define GRID (MB * 4) // 1568 = 8 * 196
#define CPX (GRID / 8)

typedef __attribute__((ext_vector_type(8))) short bf16x8;
typedef __attribute__((ext_vector_type(4))) float f32x4;

#define GLOAD16(g, l)                                                        \
    __builtin_amdgcn_global_load_lds(                                        \
        (const __attribute__((address_space(1))) unsigned int*)(g),          \
        (__attribute__((address_space(3))) unsigned int*)(l), 16, 0, 0)

__device__ __forceinline__ float bfu(unsigned short u) {
    union { float f; unsigned int i; } c;
    c.i = ((unsigned int)u) << 16;
    return c.f;
}

// ---------------------------------------------------------------------------
// detect edge_index width AND zero bcnt + stats (parallel, 256 threads)
__global__ __launch_bounds__(256) void detect_idx(const int* __restrict__ ei,
                                                  int* __restrict__ flag,
                                                  int* __restrict__ bcnt,
                                                  float* __restrict__ stats) {
    int tid = threadIdx.x;
    if (tid == 0) {
        int any = 0;
        for (int i = 0; i < 32; ++i) any |= ei[2 * i + 1];
        *flag = (any == 0) ? 1 : 0;   // 1 => int64 layout
    }
    if (tid < NBK) bcnt[tid] = 0;
    stats[tid] = 0.f;
    stats[256 + tid] = 0.f;
    stats[512 + tid] = 0.f;
    stats[768 + tid] = 0.f;
}

// ---------------------------------------------------------------------------
// FUSED: bucketA (blocks [0, ABLK)) || fp32->bf16 conversions (rest).
// bucketA: partition edges into 196 dst-buckets (dst>>8); payload packed
// (dst&255)<<16 | src. cvt part: xb, w1t, w2t.
#define XBLK  (NN * NF / 4 / 256)        // 3125
#define W1BLK (NF * NH / 256)            // 128
#define W2BLK (NH * NH / 256)            // 1024
__global__ __launch_bounds__(256) void bucketA_cvt(const void* __restrict__ eiv,
                                                   const int* __restrict__ flag,
                                                   int* __restrict__ bcnt,
                                                   int* __restrict__ ebP,
                                                   const float* __restrict__ x,
                                                   const float* __restrict__ W1,
                                                   const float* __restrict__ W2,
                                                   __hip_bfloat16* __restrict__ xb,
                                                   __hip_bfloat16* __restrict__ w1t,
                                                   __hip_bfloat16* __restrict__ w2t) {
    __shared__ int hist[NBK];
    __shared__ int lcur[NBK];
    const int tid = threadIdx.x;
    const int blk = blockIdx.x;

    if (blk >= ABLK) {   // ---- conversion blocks ----
        int bb = blk - ABLK;
        if (bb < XBLK) {
            int t = bb * 256 + tid;
            float4 v = *(const float4*)&x[t * 4];
            union { ushort4 u; __hip_bfloat16 h[4]; } o;
            o.h[0] = __float2bfloat16(v.x);
            o.h[1] = __float2bfloat16(v.y);
            o.h[2] = __float2bfloat16(v.z);
            o.h[3] = __float2bfloat16(v.w);
            *(ushort4*)&xb[t * 4] = o.u;
        } else if (bb < XBLK + W1BLK) {
            int t = (bb - XBLK) * 256 + tid;   // over NF*NH
            int n = t % NH, k = t / NH;
            w1t[n * NF + k] = __float2bfloat16(W1[t]);
        } else {
            int t = (bb - XBLK - W1BLK) * 256 + tid;   // over NH*NH
            int n = t % NH, k = t / NH;
            w2t[n * NH + k] = __float2bfloat16(W2[t]);
        }
        return;
    }

    // ---- bucketA blocks ----
    const int chunk = blk * 2048;
    const int lim = min(2048, NE - chunk);
    const bool is64 = (*flag != 0);
    const long long* ei64 = (const long long*)eiv;
    const int* ei32 = (const int*)eiv;

    for (int i = tid; i < NBK; i += 256) hist[i] = 0;
    __syncthreads();
    for (int i = tid; i < lim; i += 256) {
        int d = is64 ? (int)ei64[NE + chunk + i] : ei32[NE + chunk + i];
        atomicAdd(&hist[d >> 8], 1);
    }
    __syncthreads();
    for (int i = tid; i < NBK; i += 256) {
        int c = hist[i];
        lcur[i] = c ? atomicAdd(&bcnt[i], c) : 0;   // reserve run in bucket i
    }
    __syncthreads();
    for (int i = tid; i < lim; i += 256) {
        int s, d;
        if (is64) { s = (int)ei64[chunk + i]; d = (int)ei64[NE + chunk + i]; }
        else      { s = ei32[chunk + i];      d = ei32[NE + chunk + i]; }
        int b = d >> 8;
        int p = atomicAdd(&lcur[b], 1);             // LDS cursor -> global slot
        ebP[b * EBCAP + p] = ((d & 255) << 16) | s;
    }
}

// Bucket sort pass B: one block per bucket; computes its OWN base (masked
// scan over the 196 L2-hot bucket counts), then LDS counting sort.
__global__ __launch_bounds__(256) void bucketB(const int* __restrict__ ebP,
                                               const int* __restrict__ bcnt,
                                               int* __restrict__ rowptr,
                                               int* __restrict__ csr) {
    __shared__ int hist[256], sm[256], curs[256];
    __shared__ int baseSm;
    const int b = blockIdx.x;
    const int tid = threadIdx.x;
    const int n0 = b << 8;
    const int cnt = bcnt[b];

    // --- base = sum of bcnt[0..b-1] via in-block masked scan ---
    {
        int v = (tid < b && tid < NBK) ? bcnt[tid] : 0;
        sm[tid] = v;
        __syncthreads();
        int acc = v;
#pragma unroll
        for (int off = 1; off < 256; off <<= 1) {
            int t = (tid >= off) ? sm[tid - off] : 0;
            __syncthreads();
            acc += t;
            sm[tid] = acc;
            __syncthreads();
        }
        if (tid == 255) baseSm = acc;
        __syncthreads();
    }
    const int base = baseSm;

    hist[tid] = 0;
    __syncthreads();
    for (int i = tid; i < cnt; i += 256)
        atomicAdd(&hist[(ebP[b * EBCAP + i] >> 16) & 255], 1);
    __syncthreads();
    int v = hist[tid];
    sm[tid] = v;
    __syncthreads();
    int acc = v;
#pragma unroll
    for (int off = 1; off < 256; off <<= 1) {
        int t = (tid >= off) ? sm[tid - off] : 0;
        __syncthreads();
        acc += t;
        sm[tid] = acc;
        __syncthreads();
    }
    int excl = acc - v;
    if (n0 + tid < NN) rowptr[n0 + tid] = base + excl;   // coalesced
    curs[tid] = excl;
    __syncthreads();
    for (int i = tid; i < cnt; i += 256) {
        int p = ebP[b * EBCAP + i];
        int lp = atomicAdd(&curs[(p >> 16) & 255], 1);   // LDS cursor
        csr[base + lp] = p & 0xFFFF;
    }
    if (b == 0 && tid == 0) rowptr[NN] = NE;
}

// gather-sum, one WAVE per node, 4 neighbor rows in flight per iteration.
__global__ __launch_bounds__(256) void gather(const __hip_bfloat16* __restrict__ xb,
                                              const int* __restrict__ rowptr,
                                              const int* __restrict__ csr,
                                              __hip_bfloat16* __restrict__ h0b) {
    int n = blockIdx.x * 4 + (threadIdx.x >> 6);   // node id
    int lane = threadIdx.x & 63;
    int g = lane >> 4;
    int f4 = (lane & 15) * 4;
    if (n >= MP) return;
    if (n >= NN) {
        if (g == 0)
            *(ushort4*)&h0b[(long long)n * NF + f4] = make_ushort4(0, 0, 0, 0);
        return;
    }
    float a0 = 0.f, a1 = 0.f, a2 = 0.f, a3 = 0.f;
    if (g == 0) {   // self term
        ushort4 v = *(const ushort4*)&xb[(long long)n * NF + f4];
        a0 = bfu(v.x); a1 = bfu(v.y); a2 = bfu(v.z); a3 = bfu(v.w);
    }
    int e0 = rowptr[n], e1 = rowptr[n + 1];
    for (int e = e0 + g; e < e1; e += 4) {
        int s = csr[e];                               // broadcast within group
        ushort4 v = *(const ushort4*)&xb[(long long)s * NF + f4];
        a0 += bfu(v.x); a1 += bfu(v.y); a2 += bfu(v.z); a3 += bfu(v.w);
    }
    a0 += __shfl_xor(a0, 16); a0 += __shfl_xor(a0, 32);
    a1 += __shfl_xor(a1, 16); a1 += __shfl_xor(a1, 32);
    a2 += __shfl_xor(a2, 16); a2 += __shfl_xor(a2, 32);
    a3 += __shfl_xor(a3, 16); a3 += __shfl_xor(a3, 32);
    if (g == 0) {
        union { ushort4 u; __hip_bfloat16 h[4]; } o;
        o.h[0] = __float2bfloat16(a0);
        o.h[1] = __float2bfloat16(a1);
        o.h[2] = __float2bfloat16(a2);
        o.h[3] = __float2bfloat16(a3);
        *(ushort4*)&h0b[(long long)n * NF + f4] = o.u;
    }
}

// ---------------------------------------------------------------------------
// GEMM1 (K=64): A staged via global_load_lds (issued first), B fragments read
// direct from L1-hot w1t while the DMA is in flight; single barrier.
__global__ __launch_bounds__(256) void gemm1_staged(const __hip_bfloat16* __restrict__ A,
                                                    const __hip_bfloat16* __restrict__ BT,
                                                    const float* __restrict__ bias,
                                                    __hip_bfloat16* __restrict__ C) {
    __shared__ __hip_bfloat16 As[128 * 64];   // 16 KB
    const int orig = blockIdx.x;
    const int L = (orig & 7) * CPX + (orig >> 3);
    const int mb = L >> 2, nb = L & 3;

    const int tid = threadIdx.x;
    const int lane = tid & 63;
    const int w = tid >> 6;
    const int wm = w >> 1, wn = w & 1;
    const long long rbase = (long long)mb * 128;
    const int nbase = nb * 128;
    const int r8  = lane >> 3;
    const int swc = (lane & 7) ^ r8;      // pre-swizzled global chunk (rule #21)
    const int key = lane & 7;
    const int lo = lane & 15, hi = lane >> 4;

    {
        const __hip_bfloat16* ga = A + (rbase + w * 32 + r8) * NF + swc * 8;
        __hip_bfloat16* la = As + (w * 32) * 64;
#pragma unroll
        for (int t = 0; t < 4; ++t)
            GLOAD16(ga + t * 8 * NF, la + t * 8 * 64);
    }
    bf16x8 bfr[2][4];
#pragma unroll
    for (int ks = 0; ks < 2; ++ks)
#pragma unroll
        for (int ni = 0; ni < 4; ++ni)
            bfr[ks][ni] = *(const bf16x8*)&BT[(nbase + wn * 64 + ni * 16 + lo) * NF +
                                             ks * 32 + hi * 8];
    __syncthreads();   // A landed

    f32x4 acc[4][4];
#pragma unroll
    for (int i = 0; i < 4; ++i)
#pragma unroll
        for (int j = 0; j < 4; ++j) acc[i][j] = (f32x4){0.f, 0.f, 0.f, 0.f};

#pragma unroll
    for (int ks = 0; ks < 2; ++ks) {
        bf16x8 af[4];
#pragma unroll
        for (int mi = 0; mi < 4; ++mi)
            af[mi] = *(const bf16x8*)&As[(wm * 64 + mi * 16 + lo) * 64 +
                                         (((ks * 4 + hi) ^ key) * 8)];
#pragma unroll
        for (int mi = 0; mi < 4; ++mi)
#pragma unroll
            for (int ni = 0; ni < 4; ++ni)
                acc[mi][ni] = __builtin_amdgcn_mfma_f32_16x16x32_bf16(
                    af[mi], bfr[ks][ni], acc[mi][ni], 0, 0, 0);
    }

    const int col0 = nbase + wn * 64 + lo;
    const long long row00 = rbase + wm * 64 + hi * 4;
#pragma unroll
    for (int ni = 0; ni < 4; ++ni) {
        int col = col0 + ni * 16;
        float bv = bias[col];
#pragma unroll
        for (int mi = 0; mi < 4; ++mi) {
            long long r0 = row00 + mi * 16;
#pragma unroll
            for (int r = 0; r < 4; ++r) {
                float v = fmaxf(acc[mi][ni][r] + bv, 0.f);   // ReLU
                C[(r0 + r) * NH + col] = __float2bfloat16(v);
            }
        }
    }
}

// ---------------------------------------------------------------------------
// GEMM2 (K=512): counted-vmcnt 2-deep pipeline (R13/R16/R18 proven form).
__global__ __launch_bounds__(256) void gemm2_db(const __hip_bfloat16* __restrict__ A,
                                                const __hip_bfloat16* __restrict__ BT,
                                                const float* __restrict__ bias,
                                                __hip_bfloat16* __restrict__ C,
                                                float* __restrict__ partial) {
    constexpr int BK = 64;
    __shared__ __align__(16) char smem[65536];   // 2 sets x (A 16KB | B 16KB)
    float* smsum = (float*)smem;                 // alias set0 (dead after loop)
    float* smsq  = (float*)(smem + 2048);

    const int orig = blockIdx.x;
    const int L = (orig & 7) * CPX + (orig >> 3);
    const int mb = L >> 2, nb = L & 3;

    const int tid = threadIdx.x;
    const int lane = tid & 63;
    const int w = tid >> 6;
    const int wm = w >> 1, wn = w & 1;
    const long long rbase = (long long)mb * 128;
    const int nbase = nb * 128;
    const int r8  = lane >> 3;            // stage row within 8-row group
    const int swc = (lane & 7) ^ r8;      // pre-swizzled global chunk (rule #21)
    const int key = lane & 7;             // read-side swizzle key
    const int lo = lane & 15, hi = lane >> 4;

    const __hip_bfloat16* gaBase =
        A + (rbase + w * 32 + r8) * (long long)NH + swc * 8;
    const __hip_bfloat16* gbBase =
        BT + (long long)(nbase + w * 32 + r8) * NH + swc * 8;
    const int laOff = (w * 32) * BK;

    auto STAGE = [&](int s, int kb) {
        __hip_bfloat16* la = (__hip_bfloat16*)(smem + s * 32768) + laOff;
        __hip_bfloat16* lb = (__hip_bfloat16*)(smem + s * 32768 + 16384) + laOff;
#pragma unroll
        for (int t = 0; t < 4; ++t)
            GLOAD16(gaBase + kb + (long long)t * 8 * NH, la + t * 8 * BK);
#pragma unroll
        for (int t = 0; t < 4; ++t)
            GLOAD16(gbBase + kb + (long long)t * 8 * NH, lb + t * 8 * BK);
    };

    f32x4 acc[4][4];
#pragma unroll
    for (int i = 0; i < 4; ++i)
#pragma unroll
        for (int j = 0; j < 4; ++j) acc[i][j] = (f32x4){0.f, 0.f, 0.f, 0.f};

    // prologue: 2-deep prefetch (16 loads outstanding per wave)
    STAGE(0, 0);
    STAGE(1, BK);

#pragma unroll
    for (int t = 0; t < 8; ++t) {
        if (t == 7) { asm volatile("s_waitcnt vmcnt(0)" ::: "memory"); }
        else        { asm volatile("s_waitcnt vmcnt(8)" ::: "memory"); }
        __builtin_amdgcn_s_barrier();          // all waves' DMA for cur landed
        __builtin_amdgcn_sched_barrier(0);

        const __hip_bfloat16* Ac = (const __hip_bfloat16*)(smem + (t & 1) * 32768);
        const __hip_bfloat16* Bc = Ac + 8192;  // +16384 bytes
        __builtin_amdgcn_s_setprio(1);
#pragma unroll
        for (int ks = 0; ks < 2; ++ks) {
            bf16x8 af[4], bfr[4];
#pragma unroll
            for (int mi = 0; mi < 4; ++mi)
                af[mi] = *(const bf16x8*)&Ac[(wm * 64 + mi * 16 + lo) * BK +
                                             (((ks * 4 + hi) ^ key) * 8)];
#pragma unroll
            for (int ni = 0; ni < 4; ++ni)
                bfr[ni] = *(const bf16x8*)&Bc[(wn * 64 + ni * 16 + lo) * BK +
                                              (((ks * 4 + hi) ^ key) * 8)];
#pragma unroll
            for (int mi = 0; mi < 4; ++mi)
#pragma unroll
                for (int ni = 0; ni < 4; ++ni)
                    acc[mi][ni] = __builtin_amdgcn_mfma_f32_16x16x32_bf16(
                        af[mi], bfr[ni], acc[mi][ni], 0, 0, 0);
        }
        __builtin_amdgcn_s_setprio(0);
        __builtin_amdgcn_sched_barrier(0);
        __builtin_amdgcn_s_barrier();          // all waves done reading cur
        __builtin_amdgcn_sched_barrier(0);
        if (t < 6) STAGE(t & 1, (t + 2) * BK); // refill freed buffer, 2 ahead
    }

    // epilogue: vmcnt==0 here; full barrier before LDS alias reuse
    __syncthreads();
    if (tid < 128) { smsum[tid] = 0.f; smsq[tid] = 0.f; }
    __syncthreads();
    const int col0 = nbase + wn * 64 + lo;
    const long long row00 = rbase + wm * 64 + hi * 4;
#pragma unroll
    for (int ni = 0; ni < 4; ++ni) {
        int col = col0 + ni * 16;
        float bv = bias[col];
        float s = 0.f, q = 0.f;
#pragma unroll
        for (int mi = 0; mi < 4; ++mi) {
            long long r0 = row00 + mi * 16;
#pragma unroll
            for (int r = 0; r < 4; ++r) {
                float v = acc[mi][ni][r] + bv;
                C[(r0 + r) * NH + col] = __float2bfloat16(v);
                if ((r0 + r) < NN) { s += v; q += v * v; }
            }
        }
        s += __shfl_xor(s, 16); s += __shfl_xor(s, 32);
        q += __shfl_xor(q, 16); q += __shfl_xor(q, 32);
        if (lane < 16) {
            atomicAdd(&smsum[wn * 64 + ni * 16 + lane], s);
            atomicAdd(&smsq[wn * 64 + ni * 16 + lane], q);
        }
    }
    __syncthreads();
    if (tid < 128) {
        partial[mb * 1024 + nbase + tid] = smsum[tid];
        partial[mb * 1024 + 512 + nbase + tid] = smsq[tid];
    }
}

// widened reduce: 32 blocks = 4 j-groups x 8 mb-chunks of 49; atomic into
// the pre-zeroed stats (zeroed in detect_idx at pipeline start).
__global__ __launch_bounds__(256) void stats_reduce(const float* __restrict__ partial,
                                                    float* __restrict__ stats) {
    int j = (blockIdx.x & 3) * 256 + threadIdx.x;   // 0..1023
    int c0 = (blockIdx.x >> 2) * 49;                // 8 chunks of 49 (392)
    float s = 0.f;
    for (int mb = c0; mb < c0 + 49; ++mb) s += partial[mb * 1024 + j];
    atomicAdd(&stats[j], s);
}

// BN(train stats) + ReLU + classifier fused; bf16 h2, per-lane register params
__global__ __launch_bounds__(256) void bn_cls(const __hip_bfloat16* __restrict__ h2b,
                                              const float* __restrict__ stats,
                                              const float* __restrict__ gamma,
                                              const float* __restrict__ beta,
                                              const float* __restrict__ Wc,
                                              const float* __restrict__ bc,
                                              float* __restrict__ out) {
    int tid = threadIdx.x;
    int lane = tid & 63;
    int k0 = lane * 8;
    float sc[8], sh[8], w0[8], w1[8];
#pragma unroll
    for (int j = 0; j < 8; ++j) {
        int k = k0 + j;
        float mean = stats[k] * (1.0f / NN);
        float var = stats[512 + k] * (1.0f / NN) - mean * mean;
        float rs = rsqrtf(var + 1e-5f);
        float s = gamma[k] * rs;
        sc[j] = s;
        sh[j] = beta[k] - mean * s;
        w0[j] = Wc[2 * k];
        w1[j] = Wc[2 * k + 1];
    }
    float bc0 = bc[0], bc1 = bc[1];
    int wid = blockIdx.x * 4 + (tid >> 6);
    int nw = gridDim.x * 4;
    for (int row = wid; row < NN; row += nw) {
        bf16x8 v8 = *(const bf16x8*)&h2b[(long long)row * NH + k0];
        float a0 = 0.f, a1 = 0.f;
#pragma unroll
        for (int j = 0; j < 8; ++j) {
            float v = __bfloat162float(((const __hip_bfloat16*)&v8)[j]);
            float hn = fmaxf(fmaf(v, sc[j], sh[j]), 0.f);
            a0 = fmaf(hn, w0[j], a0);
            a1 = fmaf(hn, w1[j], a1);
        }
#pragma unroll
        for (int off = 32; off; off >>= 1) {
            a0 += __shfl_xor(a0, off);
            a1 += __shfl_xor(a1, off);
        }
        if (lane == 0) {
            out[(long long)row * 2 + 0] = a0 + bc0;
            out[(long long)row * 2 + 1] = a1 + bc1;
        }
    }
}

// ---------------------------------------------------------------------------
extern "C" void kernel_launch(void* const* d_in, const int* in_sizes, int n_in,
                              void* d_out, int out_size, void* d_ws, size_t ws_size,
                              hipStream_t stream) {
    const float* x     = (const float*)d_in[0];
    const void*  ei    = d_in[1];
    const float* W1    = (const float*)d_in[2];
    const float* b1    = (const float*)d_in[3];
    const float* W2    = (const float*)d_in[4];
    const float* b2    = (const float*)d_in[5];
    const float* gamma = (const float*)d_in[6];
    const float* beta  = (const float*)d_in[7];
    const float* Wc    = (const float*)d_in[8];
    const float* bc    = (const float*)d_in[9];
    float* out = (float*)d_out;

    // workspace carve-up (256B aligned)
    char* base = (char*)d_ws;
    size_t o = 0;
    auto alloc = [&](size_t bytes) {
        char* p = base + o;
        o = (o + bytes + 255) & ~(size_t)255;
        return p;
    };
    __hip_bfloat16* h0b     = (__hip_bfloat16*)alloc((size_t)MP * NF * 2);
    __hip_bfloat16* h1b     = (__hip_bfloat16*)alloc((size_t)MP * NH * 2);
    __hip_bfloat16* h2b     = (__hip_bfloat16*)alloc((size_t)MP * NH * 2);
    __hip_bfloat16* xb      = (__hip_bfloat16*)alloc((size_t)NN * NF * 2);
    __hip_bfloat16* w1t     = (__hip_bfloat16*)alloc((size_t)NH * NF * 2);
    __hip_bfloat16* w2t     = (__hip_bfloat16*)alloc((size_t)NH * NH * 2);
    int*            ebP     = (int*)alloc((size_t)NBK * EBCAP * 4);
    int*            bcnt    = (int*)alloc(256 * 4);
    int*            rowptr  = (int*)alloc((size_t)(NN + 1) * 4);
    int*            csr     = (int*)alloc((size_t)NE * 4);
    float*          partial = (float*)alloc((size_t)MB * 1024 * 4);
    float*          stats   = (float*)alloc(1024 * 4);
    int*            flag    = (int*)alloc(256);

    // CSR build via 2-pass LDS bucket sort; cvt fused into pass A's launch
    detect_idx<<<1, 256, 0, stream>>>((const int*)ei, flag, bcnt, stats);
    bucketA_cvt<<<ABLK + XBLK + W1BLK + W2BLK, 256, 0, stream>>>(
        ei, flag, bcnt, ebP, x, W1, W2, xb, w1t, w2t);
    bucketB<<<NBK, 256, 0, stream>>>(ebP, bcnt, rowptr, csr);

    gather<<<MP / 4, 256, 0, stream>>>(xb, rowptr, csr, h0b);

    gemm1_staged<<<GRID, 256, 0, stream>>>(h0b, w1t, b1, h1b);
    gemm2_db<<<GRID, 256, 0, stream>>>(h1b, w2t, b2, h2b, partial);

    stats_reduce<<<32, 256, 0, stream>>>(partial, stats);
    bn_cls<<<512, 256, 0, stream>>>(h2b, stats, gamma, beta, Wc, bc, out);
}